// Round 15
// baseline (342.366 us; speedup 1.0000x reference)
//
#include <hip/hip_runtime.h>
#include <hip/hip_bf16.h>
#include <hip/hip_fp16.h>
#include <math.h>

constexpr int B = 2, L = 2048, D = 1024, H = 16, DH = 64, FFD = 4096;
constexpr int S = 40;   // sample_k
constexpr int U = 40;   // n_top
constexpr float EPS = 1e-5f;
constexpr int NCHUNK = 32;
constexpr int CHLEN = L / NCHUNK;   // 64
constexpr int LD3 = 3 * D;          // QK split GEMM K' (3072)
constexpr int LD2 = 2 * D;          // QK output row stride
constexpr int LDA2 = 2 * D;         // A2 row stride [hi|lo]
constexpr int JT = 128;             // attn j-chunk
constexpr int NJC = L / JT;         // 16

typedef __attribute__((ext_vector_type(8))) short short8;      // 8 bf16/f16 bits
typedef __attribute__((ext_vector_type(8))) _Float16 half8;
typedef __attribute__((ext_vector_type(4))) float f32x4;

__device__ __forceinline__ unsigned short f2bf(float v) {
  __hip_bfloat16 h = __float2bfloat16(v);
  return __builtin_bit_cast(unsigned short, h);
}
__device__ __forceinline__ float bf2f(unsigned short u) {
  unsigned int x = ((unsigned int)u) << 16;
  return __builtin_bit_cast(float, x);
}
__device__ __forceinline__ unsigned short f2h(float v) {
  __half h = __float2half(v);
  return __builtin_bit_cast(unsigned short, h);
}
__device__ __forceinline__ float h2f(unsigned short u) {
  return __half2float(__builtin_bit_cast(__half, u));
}

__device__ __forceinline__ void gload16(const void* g, void* l) {
  __builtin_amdgcn_global_load_lds(
      (const __attribute__((address_space(1))) void*)g,
      (__attribute__((address_space(3))) void*)l, 16, 0, 0);
}

// ======== pipelined MFMA GEMM: 128xGBN tile, BK=64, DOUBLE-buffered LDS =====
// (2-barrier structure; used for V / Wo / FF2.)
template<int GBN, int MINB, bool RELU, bool OUT_BF16, bool F16, bool DUPA>
__global__ __launch_bounds__(256, MINB) void gemm_kernel(
    const unsigned short* __restrict__ A,    // [M][KA] bits
    const unsigned short* __restrict__ Bt,   // [N][K] bits
    const float* __restrict__ bias,          // [N] (or [D] when DUPA)
    const float* __restrict__ biasB,         // [D] second half when DUPA
    void* __restrict__ C, int M, int N, int K, int KA) {
  constexpr int GBM = 128, GBK = 64;
  constexpr int ABUF = GBM * GBK;
  constexpr int BBUF = GBN * GBK;
  constexpr int BUFS = ABUF + BBUF;
  constexpr int NI = GBN / 32;
  constexpr int NLOADS = 4 + GBN / 32;
  __shared__ short lds[2 * BUFS];

  const int tid  = threadIdx.x;
  const int lane = tid & 63;
  const int wid  = tid >> 6;
  const int wr = wid >> 1;
  const int wc = wid & 1;

  const int nwg  = gridDim.x * gridDim.y;
  const int orig = blockIdx.y * gridDim.x + blockIdx.x;
  const int wg   = (orig & 7) * (nwg >> 3) + (orig >> 3);
  const int bm = (wg / gridDim.x) * GBM;
  const int bn = (wg % gridDim.x) * GBN;

  const int srow  = lane >> 3;
  const int sslot = (lane & 7) ^ srow;
  const unsigned short* aS = A  + (size_t)(bm + wid * 8 + srow) * KA + sslot * 8;
  const unsigned short* bS = Bt + (size_t)(bn + wid * 8 + srow) * K  + sslot * 8;
  short* la0 = lds + wid * 8 * GBK;
  short* lb0 = lds + ABUF + wid * 8 * GBK;

  auto STAGE = [&](int buf, int kt) {
    const int akt = (DUPA && kt >= 16) ? kt - 16 : kt;
    const unsigned short* ap = aS + (size_t)akt * GBK;
    const unsigned short* bp = bS + (size_t)kt  * GBK;
    short* la = la0 + buf * BUFS;
    short* lb = lb0 + buf * BUFS;
    gload16(ap,                   la);
    gload16(ap + (size_t)32 * KA, la + 32 * GBK);
    gload16(ap + (size_t)64 * KA, la + 64 * GBK);
    gload16(ap + (size_t)96 * KA, la + 96 * GBK);
    #pragma unroll
    for (int r = 0; r < GBN / 32; ++r)
      gload16(bp + (size_t)(r * 32) * K, lb + r * 32 * GBK);
  };

  const int fr = lane & 15, g = lane >> 4;
  const int nt = K / GBK;

  STAGE(0, 0);

  f32x4 acc[4][NI] = {};
  int cur = 0;
  for (int t = 0; t < nt; ++t) {
    const int kt = (t + 1 < nt) ? t + 1 : t;
    STAGE(cur ^ 1, kt);
    if constexpr (NLOADS == 8)
      asm volatile("s_waitcnt vmcnt(8)" ::: "memory");
    else
      asm volatile("s_waitcnt vmcnt(6)" ::: "memory");
    __builtin_amdgcn_sched_barrier(0);
    __builtin_amdgcn_s_barrier();

    const short* la = lds + cur * BUFS;
    const short* lb = la + ABUF;
    short8 av[2][4], bv[2][NI];
    #pragma unroll
    for (int kk = 0; kk < 2; ++kk) {
      #pragma unroll
      for (int mi = 0; mi < 4; ++mi) {
        const int row = wr * 64 + mi * 16 + fr;
        av[kk][mi] = *(const short8*)&la[row * GBK + ((((kk << 2) | g) ^ (fr & 7)) << 3)];
      }
      #pragma unroll
      for (int ni = 0; ni < NI; ++ni) {
        const int row = wc * (GBN / 2) + ni * 16 + fr;
        bv[kk][ni] = *(const short8*)&lb[row * GBK + ((((kk << 2) | g) ^ (fr & 7)) << 3)];
      }
    }
    __builtin_amdgcn_s_setprio(1);
    #pragma unroll
    for (int kk = 0; kk < 2; ++kk)
      #pragma unroll
      for (int mi = 0; mi < 4; ++mi)
        #pragma unroll
        for (int ni = 0; ni < NI; ++ni) {
          if constexpr (F16)
            acc[mi][ni] = __builtin_amdgcn_mfma_f32_16x16x32_f16(
                __builtin_bit_cast(half8, av[kk][mi]),
                __builtin_bit_cast(half8, bv[kk][ni]), acc[mi][ni], 0, 0, 0);
          else
            acc[mi][ni] = __builtin_amdgcn_mfma_f32_16x16x32_bf16(
                av[kk][mi], bv[kk][ni], acc[mi][ni], 0, 0, 0);
        }
    __builtin_amdgcn_s_setprio(0);
    asm volatile("s_waitcnt lgkmcnt(0)" ::: "memory");
    __builtin_amdgcn_sched_barrier(0);
    __builtin_amdgcn_s_barrier();
    cur ^= 1;
  }

  #pragma unroll
  for (int ni = 0; ni < NI; ++ni) {
    const int col = bn + wc * (GBN / 2) + ni * 16 + fr;
    const float bcol = DUPA ? (col < D ? bias[col] : biasB[col - D]) : bias[col];
    #pragma unroll
    for (int mi = 0; mi < 4; ++mi) {
      #pragma unroll
      for (int j = 0; j < 4; ++j) {
        const int rowg = bm + wr * 64 + mi * 16 + (g << 2) + j;
        float v = acc[mi][ni][j] + bcol;
        if (RELU) v = fmaxf(v, 0.f);
        if (OUT_BF16) ((unsigned short*)C)[(size_t)rowg * N + col] = f2bf(v);
        else          ((float*)C)[(size_t)rowg * N + col] = v;
      }
    }
  }
}

// ======== 8-phase 256x128 MFMA GEMM for QK (M=4096, N=2048, K'=3072) ========
// f16 3-term split (DUPA remap), 8 waves (4M x 2N), wave C = 64x64 (acc[4][4]),
// BK=64, 2 x 48KB LDS dbuf (96 KB -> 1 block/CU), counted vmcnt(2)
// (part0 of t+1 issued BEFORE the wait; in-order retirement => tile t
// resident), 2 compute phases/K-tile with stage parts interleaved, setprio,
// barriers only at tile boundaries. Split bias (col<D -> bq else bk), f32 out.
__global__ __launch_bounds__(512, 1) void gemm_qk_8ph_kernel(
    const unsigned short* __restrict__ A,    // [M][KA=2048] f16 [hi|lo]
    const unsigned short* __restrict__ Bt,   // [N][K=3072] f16 [Whi|Wlo|Whi]
    const float* __restrict__ bias,          // bq [D]
    const float* __restrict__ biasB,         // bk [D]
    float* __restrict__ C, int M, int N, int K, int KA) {
  constexpr int BK = 64;
  constexpr int ABUF = 256 * BK;   // 16384 shorts
  constexpr int BBUF = 128 * BK;   // 8192 shorts
  constexpr int BUFS = ABUF + BBUF;
  __shared__ short lds[2 * BUFS];  // 96 KB

  const int tid  = threadIdx.x;
  const int lane = tid & 63;
  const int wid  = tid >> 6;          // 0..7
  const int wrm  = wid >> 1;          // 0..3 (64-row band)
  const int wcn  = wid & 1;           // 0..1 (64-col band)

  const int nwg  = gridDim.x * gridDim.y;      // 256
  const int orig = blockIdx.y * gridDim.x + blockIdx.x;
  const int wg   = (orig & 7) * (nwg >> 3) + (orig >> 3);
  const int bm = (wg / gridDim.x) * 256;
  const int bn = (wg % gridDim.x) * 128;

  const int srow  = lane >> 3;
  const int sslot = (lane & 7) ^ srow;
  const unsigned short* aS = A  + (size_t)(bm + wid * 8 + srow) * KA + sslot * 8;
  const unsigned short* bS = Bt + (size_t)(bn + wid * 8 + srow) * K  + sslot * 8;
  short* ldsA0 = lds + wid * 8 * BK;
  short* ldsB0 = lds + ABUF + wid * 8 * BK;

  auto STAGE2 = [&](int buf, int kt, int part) {   // 2 gload16 / thread
    const int akt = (kt >= 16) ? kt - 16 : kt;     // 3-term DUPA remap
    if (part < 2) {
      const unsigned short* ap = aS + (size_t)akt * BK;
      short* la = ldsA0 + buf * BUFS;
      const int r0 = part * 128;
      gload16(ap + (size_t)r0 * KA,        la + r0 * BK);
      gload16(ap + (size_t)(r0 + 64) * KA, la + (r0 + 64) * BK);
    } else {
      const unsigned short* bp = bS + (size_t)kt * BK;
      short* lb = ldsB0 + buf * BUFS;
      gload16(bp,                  lb);
      gload16(bp + (size_t)64 * K, lb + 64 * BK);
    }
  };

  const int fr = lane & 15, g = lane >> 4;
  const int nt = K / BK;   // 48

  STAGE2(0, 0, 0); STAGE2(0, 0, 1); STAGE2(0, 0, 2);

  f32x4 acc[4][4] = {};
  short8 av[2][4], bv0[2][2], bv1[2][2];
  int bc = 0;
  for (int t = 0; t < nt; ++t) {
    const int kt = (t + 1 < nt) ? t + 1 : t;       // clamp keeps vmcnt uniform
    const short* la = lds + bc * BUFS;
    const short* lb = la + ABUF;

    STAGE2(bc ^ 1, kt, 0);
    asm volatile("s_waitcnt vmcnt(2)" ::: "memory"); // tile t (6 oldest) retired
    __builtin_amdgcn_sched_barrier(0);
    __builtin_amdgcn_s_barrier();

    // ---- P0: read av(all) + bv0(ni 0,1); MFMA half (ni 0,1) ----
    #pragma unroll
    for (int kk = 0; kk < 2; ++kk) {
      #pragma unroll
      for (int mi = 0; mi < 4; ++mi) {
        const int row = wrm * 64 + mi * 16 + fr;
        av[kk][mi] = *(const short8*)&la[row * BK + ((((kk << 2) | g) ^ (fr & 7)) << 3)];
      }
      #pragma unroll
      for (int ni = 0; ni < 2; ++ni) {
        const int row = wcn * 64 + ni * 16 + fr;
        bv0[kk][ni] = *(const short8*)&lb[row * BK + ((((kk << 2) | g) ^ (fr & 7)) << 3)];
      }
    }
    asm volatile("s_waitcnt lgkmcnt(0)" ::: "memory");
    __builtin_amdgcn_sched_barrier(0);
    __builtin_amdgcn_s_setprio(1);
    #pragma unroll
    for (int kk = 0; kk < 2; ++kk)
      #pragma unroll
      for (int mi = 0; mi < 4; ++mi)
        #pragma unroll
        for (int ni = 0; ni < 2; ++ni)
          acc[mi][ni] = __builtin_amdgcn_mfma_f32_16x16x32_f16(
              __builtin_bit_cast(half8, av[kk][mi]),
              __builtin_bit_cast(half8, bv0[kk][ni]), acc[mi][ni], 0, 0, 0);
    __builtin_amdgcn_s_setprio(0);

    STAGE2(bc ^ 1, kt, 1);
    // ---- P1: read bv1(ni 2,3); MFMA half (ni 2,3) ----
    #pragma unroll
    for (int kk = 0; kk < 2; ++kk)
      #pragma unroll
      for (int ni = 0; ni < 2; ++ni) {
        const int row = wcn * 64 + 32 + ni * 16 + fr;
        bv1[kk][ni] = *(const short8*)&lb[row * BK + ((((kk << 2) | g) ^ (fr & 7)) << 3)];
      }
    asm volatile("s_waitcnt lgkmcnt(0)" ::: "memory");
    __builtin_amdgcn_sched_barrier(0);
    __builtin_amdgcn_s_setprio(1);
    #pragma unroll
    for (int kk = 0; kk < 2; ++kk)
      #pragma unroll
      for (int mi = 0; mi < 4; ++mi)
        #pragma unroll
        for (int ni = 0; ni < 2; ++ni)
          acc[mi][2 + ni] = __builtin_amdgcn_mfma_f32_16x16x32_f16(
              __builtin_bit_cast(half8, av[kk][mi]),
              __builtin_bit_cast(half8, bv1[kk][ni]), acc[mi][2 + ni], 0, 0, 0);
    __builtin_amdgcn_s_setprio(0);

    STAGE2(bc ^ 1, kt, 2);
    __builtin_amdgcn_s_barrier();   // all waves done reading buf bc
    bc ^= 1;
  }

  // epilogue: C/D layout col=lane&15, row=(lane>>4)*4+reg
  #pragma unroll
  for (int ni = 0; ni < 4; ++ni) {
    const int col = bn + wcn * 64 + ni * 16 + fr;
    const float bcol = (col < D) ? bias[col] : biasB[col - D];
    #pragma unroll
    for (int mi = 0; mi < 4; ++mi) {
      #pragma unroll
      for (int j = 0; j < 4; ++j) {
        const int rowg = bm + wrm * 64 + mi * 16 + (g << 2) + j;
        C[(size_t)rowg * N + col] = acc[mi][ni][j] + bcol;
      }
    }
  }
}

// ======== 8-phase 256x256 MFMA GEMM (FF1: M=4096,N=4096,K=1024) =============
__global__ __launch_bounds__(512, 1) void gemm_ff1_8ph_kernel(
    const unsigned short* __restrict__ A,    // [M][K] bf16 bits
    const unsigned short* __restrict__ Bt,   // [N][K] bf16 bits
    const float* __restrict__ bias,          // [N]
    unsigned short* __restrict__ C, int M, int N, int K) {
  constexpr int BK = 64;
  __shared__ short lds8[2 * 32768];   // 128 KB

  const int tid  = threadIdx.x;
  const int lane = tid & 63;
  const int wid  = tid >> 6;
  const int wrm  = wid >> 2;
  const int wcn  = wid & 3;

  const int nwg  = gridDim.x * gridDim.y;
  const int orig = blockIdx.y * gridDim.x + blockIdx.x;
  const int wg   = (orig & 7) * (nwg >> 3) + (orig >> 3);
  const int bm = (wg / gridDim.x) * 256;
  const int bn = (wg % gridDim.x) * 256;

  const int srow  = lane >> 3;
  const int sslot = (lane & 7) ^ srow;
  const unsigned short* aS = A  + (size_t)(bm + wid * 8 + srow) * K + sslot * 8;
  const unsigned short* bS = Bt + (size_t)(bn + wid * 8 + srow) * K + sslot * 8;
  short* ldsA0 = lds8 + wid * 8 * BK;
  short* ldsB0 = lds8 + 16384 + wid * 8 * BK;

  auto STAGE2 = [&](int buf, int kt, int part) {
    if (part < 2) {
      const unsigned short* ap = aS + (size_t)kt * BK;
      short* la = ldsA0 + buf * 32768;
      const int r0 = part * 128;
      gload16(ap + (size_t)r0 * K,        la + r0 * BK);
      gload16(ap + (size_t)(r0 + 64) * K, la + (r0 + 64) * BK);
    } else {
      const unsigned short* bp = bS + (size_t)kt * BK;
      short* lb = ldsB0 + buf * 32768;
      const int r0 = (part - 2) * 128;
      gload16(bp + (size_t)r0 * K,        lb + r0 * BK);
      gload16(bp + (size_t)(r0 + 64) * K, lb + (r0 + 64) * BK);
    }
  };

  const int fr = lane & 15, g = lane >> 4;
  const int nt = K / BK;

  #pragma unroll
  for (int p = 0; p < 4; ++p) STAGE2(0, 0, p);

  f32x4 acc[8][4] = {};
  short8 av[2][4], bv0[2][2], bv1[2][2];
  int bc = 0;
  for (int t = 0; t < nt; ++t) {
    const int kt = (t + 1 < nt) ? t + 1 : t;
    const short* la = lds8 + bc * 32768;
    const short* lb = la + 16384;

    STAGE2(bc ^ 1, kt, 0);
    asm volatile("s_waitcnt vmcnt(2)" ::: "memory");
    __builtin_amdgcn_sched_barrier(0);
    __builtin_amdgcn_s_barrier();

    #pragma unroll
    for (int kk = 0; kk < 2; ++kk) {
      #pragma unroll
      for (int mi = 0; mi < 4; ++mi) {
        const int row = wrm * 128 + mi * 16 + fr;
        av[kk][mi] = *(const short8*)&la[row * BK + ((((kk << 2) | g) ^ (fr & 7)) << 3)];
      }
      #pragma unroll
      for (int ni = 0; ni < 2; ++ni) {
        const int row = wcn * 64 + ni * 16 + fr;
        bv0[kk][ni] = *(const short8*)&lb[row * BK + ((((kk << 2) | g) ^ (fr & 7)) << 3)];
      }
    }
    asm volatile("s_waitcnt lgkmcnt(0)" ::: "memory");
    __builtin_amdgcn_sched_barrier(0);
    __builtin_amdgcn_s_setprio(1);
    #pragma unroll
    for (int kk = 0; kk < 2; ++kk)
      #pragma unroll
      for (int mi = 0; mi < 4; ++mi)
        #pragma unroll
        for (int ni = 0; ni < 2; ++ni)
          acc[mi][ni] = __builtin_amdgcn_mfma_f32_16x16x32_bf16(
              av[kk][mi], bv0[kk][ni], acc[mi][ni], 0, 0, 0);
    __builtin_amdgcn_s_setprio(0);

    STAGE2(bc ^ 1, kt, 1);
    #pragma unroll
    for (int kk = 0; kk < 2; ++kk)
      #pragma unroll
      for (int ni = 0; ni < 2; ++ni) {
        const int row = wcn * 64 + 32 + ni * 16 + fr;
        bv1[kk][ni] = *(const short8*)&lb[row * BK + ((((kk << 2) | g) ^ (fr & 7)) << 3)];
      }
    asm volatile("s_waitcnt lgkmcnt(0)" ::: "memory");
    __builtin_amdgcn_sched_barrier(0);
    __builtin_amdgcn_s_setprio(1);
    #pragma unroll
    for (int kk = 0; kk < 2; ++kk)
      #pragma unroll
      for (int mi = 0; mi < 4; ++mi)
        #pragma unroll
        for (int ni = 0; ni < 2; ++ni)
          acc[mi][2 + ni] = __builtin_amdgcn_mfma_f32_16x16x32_bf16(
              av[kk][mi], bv1[kk][ni], acc[mi][2 + ni], 0, 0, 0);
    __builtin_amdgcn_s_setprio(0);

    STAGE2(bc ^ 1, kt, 2);
    #pragma unroll
    for (int kk = 0; kk < 2; ++kk)
      #pragma unroll
      for (int mi = 0; mi < 4; ++mi) {
        const int row = wrm * 128 + 64 + mi * 16 + fr;
        av[kk][mi] = *(const short8*)&la[row * BK + ((((kk << 2) | g) ^ (fr & 7)) << 3)];
      }
    asm volatile("s_waitcnt lgkmcnt(0)" ::: "memory");
    __builtin_amdgcn_sched_barrier(0);
    __builtin_amdgcn_s_setprio(1);
    #pragma unroll
    for (int kk = 0; kk < 2; ++kk)
      #pragma unroll
      for (int mi = 0; mi < 4; ++mi)
        #pragma unroll
        for (int ni = 0; ni < 2; ++ni)
          acc[4 + mi][ni] = __builtin_amdgcn_mfma_f32_16x16x32_bf16(
              av[kk][mi], bv0[kk][ni], acc[4 + mi][ni], 0, 0, 0);
    __builtin_amdgcn_s_setprio(0);

    STAGE2(bc ^ 1, kt, 3);
    __builtin_amdgcn_s_setprio(1);
    #pragma unroll
    for (int kk = 0; kk < 2; ++kk)
      #pragma unroll
      for (int mi = 0; mi < 4; ++mi)
        #pragma unroll
        for (int ni = 0; ni < 2; ++ni)
          acc[4 + mi][2 + ni] = __builtin_amdgcn_mfma_f32_16x16x32_bf16(
              av[kk][mi], bv1[kk][ni], acc[4 + mi][2 + ni], 0, 0, 0);
    __builtin_amdgcn_s_setprio(0);
    __builtin_amdgcn_s_barrier();
    bc ^= 1;
  }

  #pragma unroll
  for (int NJ = 0; NJ < 4; ++NJ) {
    const int col = bn + wcn * 64 + NJ * 16 + fr;
    const float bcol = bias[col];
    #pragma unroll
    for (int MI = 0; MI < 8; ++MI) {
      #pragma unroll
      for (int j = 0; j < 4; ++j) {
        const int rowg = bm + wrm * 128 + MI * 16 + (g << 2) + j;
        float v = fmaxf(acc[MI][NJ][j] + bcol, 0.f);
        C[(size_t)rowg * N + col] = f2bf(v);
      }
    }
  }
}

// ===== fused prep (one launch, block ranges): =====
__global__ __launch_bounds__(256) void prep_kernel(
    const float* __restrict__ x, unsigned short* __restrict__ A2,
    unsigned short* __restrict__ xb,
    const float* __restrict__ Wq, const float* __restrict__ Wk,
    unsigned short* __restrict__ B2r,
    const float* __restrict__ Wv, const float* __restrict__ Wo,
    const float* __restrict__ W1, const float* __restrict__ W2,
    unsigned short* __restrict__ Wvt, unsigned short* __restrict__ Wot,
    unsigned short* __restrict__ W1t, unsigned short* __restrict__ W2t) {
  const int bid = blockIdx.x;
  __shared__ float tile[32][33];
  if (bid < 4096) {
    const int i = (bid * 256 + threadIdx.x) * 4;
    const int m = i / D, k = i % D;
    const float4 v = *(const float4*)(x + i);
    ushort4 hi, lo, bb;
    hi.x = f2h(v.x); lo.x = f2h(v.x - h2f(hi.x)); bb.x = f2bf(v.x);
    hi.y = f2h(v.y); lo.y = f2h(v.y - h2f(hi.y)); bb.y = f2bf(v.y);
    hi.z = f2h(v.z); lo.z = f2h(v.z - h2f(hi.z)); bb.z = f2bf(v.z);
    hi.w = f2h(v.w); lo.w = f2h(v.w - h2f(hi.w)); bb.w = f2bf(v.w);
    unsigned short* row = A2 + (size_t)m * LDA2;
    *(ushort4*)(row + k)     = hi;
    *(ushort4*)(row + D + k) = lo;
    *(ushort4*)(xb + i) = bb;
    return;
  }
  const int tx = threadIdx.x & 31, ty = threadIdx.x >> 5;
  if (bid < 6144) {
    const int t = bid - 4096;
    const int z = t >> 10;
    const float* W = z ? Wk : Wq;
    unsigned short* outb = B2r + (size_t)z * D * LD3;
    const int bx = ((t & 1023) & 31) * 32;
    const int by = ((t & 1023) >> 5) * 32;
    #pragma unroll
    for (int i = ty; i < 32; i += 8)
      tile[i][tx] = W[(size_t)(by + i) * D + bx + tx];
    __syncthreads();
    #pragma unroll
    for (int i = ty; i < 32; i += 8) {
      const float v = tile[tx][i];
      const unsigned short hi = f2h(v);
      const unsigned short lo = f2h(v - h2f(hi));
      unsigned short* r = outb + (size_t)(bx + i) * LD3 + (by + tx);
      r[0]     = hi;
      r[D]     = lo;
      r[2 * D] = hi;
    }
    return;
  }
  const int tb = bid - 6144;
  const float* W; unsigned short* Wt; int K, N, t;
  if (tb < 1024)      { W = Wv; Wt = Wvt; K = D;   N = D;   t = tb; }
  else if (tb < 2048) { W = Wo; Wt = Wot; K = D;   N = D;   t = tb - 1024; }
  else if (tb < 6144) { W = W1; Wt = W1t; K = D;   N = FFD; t = tb - 2048; }
  else                { W = W2; Wt = W2t; K = FFD; N = D;   t = tb - 6144; }
  const int nx = N / 32;
  const int bx = (t % nx) * 32;
  const int by = (t / nx) * 32;
  #pragma unroll
  for (int i = ty; i < 32; i += 8)
    tile[i][tx] = W[(size_t)(by + i) * N + bx + tx];
  __syncthreads();
  #pragma unroll
  for (int i = ty; i < 32; i += 8)
    Wt[(size_t)(bx + i) * K + by + tx] = f2bf(tile[tx][i]);
}

// ------------- M[b,h,l] = max_s(Q[l]·K[idx[l,s]]) - sum_s(...)/L ------------
__global__ __launch_bounds__(256) void prob_m_kernel(
    const float* __restrict__ QK, const int* __restrict__ idx,
    float* __restrict__ M_) {
  const int combo = blockIdx.x;
  const int b = combo >> 2, hg = combo & 3;
  const int l = blockIdx.y;
  const int tid = threadIdx.x;
  const int wave = tid >> 6;
  const int lane = tid & 63;
  const int h = hg * 4 + wave;
  __shared__ int sidx[S];
  if (tid < S) sidx[tid] = idx[l * S + tid];
  __syncthreads();
  const int dsub = (lane & 15) * 4;
  const int sgrp = lane >> 4;
  const float4 q = *(const float4*)(QK + ((size_t)b * L + l) * LD2 + h * DH + dsub);
  float mx = -INFINITY, sm = 0.f;
  for (int s = sgrp; s < S; s += 4) {
    const float4 kv = *(const float4*)(QK + ((size_t)b * L + sidx[s]) * LD2 + D + h * DH + dsub);
    float p = q.x*kv.x + q.y*kv.y + q.z*kv.z + q.w*kv.w;
    p += __shfl_xor(p, 1);
    p += __shfl_xor(p, 2);
    p += __shfl_xor(p, 4);
    p += __shfl_xor(p, 8);
    mx = fmaxf(mx, p);
    sm += p;
  }
  mx = fmaxf(mx, __shfl_xor(mx, 16));
  mx = fmaxf(mx, __shfl_xor(mx, 32));
  sm += __shfl_xor(sm, 16);
  sm += __shfl_xor(sm, 32);
  if (lane == 0)
    M_[((size_t)b * H + h) * L + l] = mx - sm / (float)L;
}

// ---- exact top-k (k=40, n=2048): single wave, register-resident, no LDS ----
__global__ __launch_bounds__(64) void topk_kernel(
    const float* __restrict__ M_, int* __restrict__ Mtop) {
  const int bh = blockIdx.x;
  const float* row = M_ + (size_t)bh * L;
  const int lane = threadIdx.x;
  float v[32];
  #pragma unroll
  for (int k = 0; k < 32; ++k) v[k] = row[k * 64 + lane];
  for (int u = 0; u < U; ++u) {
    float best = v[0]; int bk = 0;
    #pragma unroll
    for (int k = 1; k < 32; ++k)
      if (v[k] > best) { best = v[k]; bk = k; }
    int bidx = bk * 64 + lane;
    #pragma unroll
    for (int off = 1; off < 64; off <<= 1) {
      const float ov = __shfl_xor(best, off);
      const int   oi = __shfl_xor(bidx, off);
      if (ov > best || (ov == best && oi < bidx)) { best = ov; bidx = oi; }
    }
    if (lane == 0) Mtop[bh * U + u] = bidx;
    if ((bidx & 63) == lane) {
      const int kk = bidx >> 6;
      #pragma unroll
      for (int k = 0; k < 32; ++k) if (k == kk) v[k] = -INFINITY;
    }
  }
}

// ------- attn phase 1: per (b,h,jc) partial softmax + PV over 128 keys ------
__global__ __launch_bounds__(320) void attn_p1_kernel(
    const float* __restrict__ QK, const unsigned short* __restrict__ V16,
    const int* __restrict__ Mtop,
    float* __restrict__ pmax, float* __restrict__ psum, float* __restrict__ pv) {
  const int jc = blockIdx.x, h = blockIdx.y, b = blockIdx.z;
  const int bh = b * H + h;
  const int tid = threadIdx.x;
  const int j0 = jc * JT;
  __shared__ float Qs[U][68];
  __shared__ float KVs[JT][68];
  __shared__ unsigned short ws[U][JT];

  for (int i = tid; i < U * 16; i += 320) {
    const int u = i >> 4, dq = (i & 15) << 2;
    const int row = Mtop[bh * U + u];
    *(float4*)&Qs[u][dq] =
        *(const float4*)(QK + ((size_t)b * L + row) * LD2 + h * DH + dq);
  }
  for (int i = tid; i < JT * 16; i += 320) {
    const int j = i >> 4, dq = (i & 15) << 2;
    *(float4*)&KVs[j][dq] =
        *(const float4*)(QK + ((size_t)b * L + j0 + j) * LD2 + D + h * DH + dq);
  }
  __syncthreads();

  const int u = tid >> 3, jg = tid & 7;
  const int mt = Mtop[bh * U + u];
  float sc[16];
  #pragma unroll
  for (int jt = 0; jt < 16; ++jt) sc[jt] = 0.f;
  for (int dq = 0; dq < 64; dq += 4) {
    const float4 q = *(const float4*)&Qs[u][dq];
    #pragma unroll
    for (int jt = 0; jt < 16; ++jt) {
      const float4 k = *(const float4*)&KVs[jt * 8 + jg][dq];
      sc[jt] += q.x*k.x + q.y*k.y + q.z*k.z + q.w*k.w;
    }
  }
  float m = -INFINITY;
  #pragma unroll
  for (int jt = 0; jt < 16; ++jt) {
    const int j = j0 + jt * 8 + jg;
    sc[jt] = (j <= mt) ? sc[jt] * 0.125f : -INFINITY;
    m = fmaxf(m, sc[jt]);
  }
  m = fmaxf(m, __shfl_xor(m, 1));
  m = fmaxf(m, __shfl_xor(m, 2));
  m = fmaxf(m, __shfl_xor(m, 4));
  float sum = 0.f;
  #pragma unroll
  for (int jt = 0; jt < 16; ++jt) {
    const float e = (sc[jt] == -INFINITY) ? 0.f : expf(sc[jt] - m);
    sum += e;
    ws[u][jt * 8 + jg] = f2bf(e);
  }
  sum += __shfl_xor(sum, 1);
  sum += __shfl_xor(sum, 2);
  sum += __shfl_xor(sum, 4);
  if (jg == 0) {
    pmax[(size_t)(bh * NJC + jc) * U + u] = m;
    psum[(size_t)(bh * NJC + jc) * U + u] = sum;
  }
  __syncthreads();
  for (int i = tid; i < JT * 8; i += 320) {
    const int j = i >> 3, d8 = (i & 7) << 3;
    short8 vv = *(const short8*)(V16 + ((size_t)b * L + j0 + j) * D + h * DH + d8);
    #pragma unroll
    for (int e = 0; e < 8; ++e)
      KVs[j][d8 + e] = bf2f((unsigned short)vv[e]);
  }
  __syncthreads();
  const int d = tid & 63, ug = tid >> 6;
  float acc[8] = {};
  for (int j = 0; j < JT; j += 2) {
    const float v0 = KVs[j][d], v1 = KVs[j + 1][d];
    #pragma unroll
    for (int k = 0; k < 8; ++k) {
      const int uu = ug + k * 5;
      const unsigned int wp = *(const unsigned int*)&ws[uu][j];
      acc[k] = fmaf(bf2f((unsigned short)(wp & 0xffff)), v0, acc[k]);
      acc[k] = fmaf(bf2f((unsigned short)(wp >> 16)), v1, acc[k]);
    }
  }
  #pragma unroll
  for (int k = 0; k < 8; ++k) {
    const int uu = ug + k * 5;
    pv[((size_t)(bh * NJC + jc) * U + uu) * DH + d] = acc[k];
  }
}

// -- attn phase 2: combine 16 chunks per (b,h,u), scatter into ctx16 (bf16) --
__global__ __launch_bounds__(64) void attn_p2_kernel(
    const float* __restrict__ pmax, const float* __restrict__ psum,
    const float* __restrict__ pv, const int* __restrict__ Mtop,
    unsigned short* __restrict__ ctx16) {
  const int bid = blockIdx.x;
  const int u = bid % U, bh = bid / U;
  const int d = threadIdx.x;
  float gmax = -INFINITY;
  for (int c = 0; c < NJC; ++c)
    gmax = fmaxf(gmax, pmax[(size_t)(bh * NJC + c) * U + u]);
  float den = 0.f, num = 0.f;
  for (int c = 0; c < NJC; ++c) {
    const float m = pmax[(size_t)(bh * NJC + c) * U + u];
    if (m == -INFINITY) continue;
    const float s = expf(m - gmax);
    den += psum[(size_t)(bh * NJC + c) * U + u] * s;
    num += pv[((size_t)(bh * NJC + c) * U + u) * DH + d] * s;
  }
  const int h = bh % H, b = bh / H;
  const int l = Mtop[bh * U + u];
  ctx16[((size_t)b * L + l) * D + h * DH + d] = f2bf(num / den);
}

// --------- cumsum(V16) over l: pass1 = per-chunk column sums only -----------
__global__ __launch_bounds__(256) void cumsum_pass1(
    const unsigned short* __restrict__ V16, float* __restrict__ csums) {
  const int cp = blockIdx.x * 256 + threadIdx.x;
  const int ch = blockIdx.y, b = blockIdx.z;
  size_t base = ((size_t)b * L + (size_t)ch * CHLEN) * D + cp * 2;
  float a0 = 0.f, a1 = 0.f;
  for (int i = 0; i < CHLEN; ++i) {
    const unsigned int u = *(const unsigned int*)(V16 + base + (size_t)i * D);
    a0 += bf2f((unsigned short)(u & 0xffff));
    a1 += bf2f((unsigned short)(u >> 16));
  }
  float* cs = csums + ((size_t)b * NCHUNK + ch) * D + cp * 2;
  cs[0] = a0; cs[1] = a1;
}

__global__ __launch_bounds__(256) void cumsum_pass2(
    const unsigned short* __restrict__ V16, const float* __restrict__ csums,
    unsigned short* __restrict__ ctx16) {
  const int cp = blockIdx.x * 256 + threadIdx.x;
  const int ch = blockIdx.y, b = blockIdx.z;
  float a0 = 0.f, a1 = 0.f;
  for (int j = 0; j < ch; ++j) {
    const float* cs = csums + ((size_t)b * NCHUNK + j) * D + cp * 2;
    a0 += cs[0]; a1 += cs[1];
  }
  size_t base = ((size_t)b * L + (size_t)ch * CHLEN) * D + cp * 2;
  for (int i = 0; i < CHLEN; ++i) {
    const size_t o = base + (size_t)i * D;
    const unsigned int u = *(const unsigned int*)(V16 + o);
    a0 += bf2f((unsigned short)(u & 0xffff));
    a1 += bf2f((unsigned short)(u >> 16));
    *(unsigned int*)(ctx16 + o) =
        (unsigned int)f2bf(a0) | ((unsigned int)f2bf(a1) << 16);
  }
}

// -- out = LayerNorm(a + r)*g + be; wave-per-row (4 rows/block, shfl reduce) -
template<bool ABF16>
__global__ __launch_bounds__(256) void add_ln_kernel(
    const void* __restrict__ a_, const unsigned short* __restrict__ r,
    const float* __restrict__ g, const float* __restrict__ be,
    float* __restrict__ out, unsigned short* __restrict__ out16) {
  const int row  = blockIdx.x * 4 + (threadIdx.x >> 6);
  const int lane = threadIdx.x & 63;
  float v[16];
  float s = 0.f;
  #pragma unroll
  for (int j = 0; j < 4; ++j) {
    const int c = j * 256 + lane * 4;
    float4 av;
    if (ABF16) {
      ushort4 ua = *(const ushort4*)((const unsigned short*)a_ + (size_t)row * D + c);
      av.x = bf2f(ua.x); av.y = bf2f(ua.y); av.z = bf2f(ua.z); av.w = bf2f(ua.w);
    } else {
      av = *(const float4*)((const float*)a_ + (size_t)row * D + c);
    }
    const ushort4 ur = *(const ushort4*)(r + (size_t)row * D + c);
    v[j*4+0] = av.x + bf2f(ur.x);
    v[j*4+1] = av.y + bf2f(ur.y);
    v[j*4+2] = av.z + bf2f(ur.z);
    v[j*4+3] = av.w + bf2f(ur.w);
    s += v[j*4+0] + v[j*4+1] + v[j*4+2] + v[j*4+3];
  }
  #pragma unroll
  for (int off = 1; off < 64; off <<= 1) s += __shfl_xor(s, off);
  const float mu = s / (float)D;
  float s2 = 0.f;
  #pragma unroll
  for (int k = 0; k < 16; ++k) { const float dv = v[k] - mu; s2 += dv * dv; }
  #pragma unroll
  for (int off = 1; off < 64; off <<= 1) s2 += __shfl_xor(s2, off);
  const float rstd = rsqrtf(s2 / (float)D + EPS);
  #pragma unroll
  for (int j = 0; j < 4; ++j) {
    const int c = j * 256 + lane * 4;
    const float4 gv = *(const float4*)(g + c);
    const float4 bv = *(const float4*)(be + c);
    float o0 = (v[j*4+0] - mu) * rstd * gv.x + bv.x;
    float o1 = (v[j*4+1] - mu) * rstd * gv.y + bv.y;
    float o2 = (v[j*4+2] - mu) * rstd * gv.z + bv.z;
    float o3 = (v[j*4+3] - mu) * rstd * gv.w + bv.w;
    if (out) {
      float4 ov; ov.x = o0; ov.y = o1; ov.z = o2; ov.w = o3;
      *(float4*)(out + (size_t)row * D + c) = ov;
    }
    if (out16) {
      ushort4 uo;
      uo.x = f2bf(o0); uo.y = f2bf(o1); uo.z = f2bf(o2); uo.w = f2bf(o3);
      *(ushort4*)(out16 + (size_t)row * D + c) = uo;
    }
  }
}

// ----------------------------------------------------------------------------
extern "C" void kernel_launch(void* const* d_in, const int* in_sizes, int n_in,
                              void* d_out, int out_size, void* d_ws, size_t ws_size,
                              hipStream_t stream) {
  const float* x   = (const float*)d_in[0];
  const float* Wq  = (const float*)d_in[1];
  const float* bq  = (const float*)d_in[2];
  const float* Wk  = (const float*)d_in[3];
  const float* bk  = (const float*)d_in[4];
  const float* Wv  = (const float*)d_in[5];
  const float* bv  = (const float*)d_in[6];
  const float* Wo  = (const float*)d_in[7];
  const float* bo  = (const float*)d_in[8];
  const float* g1  = (const float*)d_in[9];
  const float* be1 = (const float*)d_in[10];
  const float* W1  = (const float*)d_in[11];
  const float* b1  = (const float*)d_in[12];
  const float* W2  = (const float*)d_in[13];
  const float* b2  = (const float*)d_in[14];
  const float* g2  = (const float*)d_in[15];
  const float* be2 = (const float*)d_in[16];
  const int*   idx = (const int*)d_in[17];
  float* out = (float*)d_out;

  char* p = (char*)d_ws;
  unsigned short* A2     = (unsigned short*)p;
  unsigned short* AO16   = (unsigned short*)p;
  unsigned short* ff2_16 = (unsigned short*)(p + 8388608);
  unsigned short* xb    = (unsigned short*)(p + 16777216);
  unsigned short* ctx16 = (unsigned short*)(p + 16777216);
  unsigned short* B2 = (unsigned short*)(p + 25165824);
  char* scr = p + 25165824;
  float* Mbuf   = (float*)(scr);
  float* csum   = (float*)(scr + 262144);
  int*   Mtop   = (int*)  (scr + 524288);
  float* pmax   = (float*)(scr + 532480);
  float* psum   = (float*)(scr + 614400);
  float* pv     = (float*)(scr + 696320);
  float*          QKb = (float*)(p + 37748736);
  unsigned short* x1b = (unsigned short*)(p + 54525952);
  unsigned short* ff1b = (unsigned short*)(p + 62914560);
  unsigned short* Vb16 = (unsigned short*)(p + 96468992);
  unsigned short* Wvt = (unsigned short*)(p + 113246208);
  unsigned short* Wot = (unsigned short*)(p + 115343360);
  unsigned short* W1t = (unsigned short*)(p + 117440512);
  unsigned short* W2t = (unsigned short*)(p + 125829120);

  dim3 blk(256);
  const int M = B * L;   // 4096

  // 1) fused prep
  prep_kernel<<<16384, blk, 0, stream>>>(x, A2, xb, Wq, Wk, B2,
                                         Wv, Wo, W1, W2, Wvt, Wot, W1t, W2t);
  // 2) QK via 8-phase 256x128 f16 3-term split (fp32-accurate, selection-safe)
  gemm_qk_8ph_kernel<<<dim3(LD2/128, M/256), dim3(512), 0, stream>>>(
      A2, B2, bq, bk, QKb, M, LD2, LD3, LDA2);
  // 3) V projection -> bf16
  gemm_kernel<64,3,false,true,false,false><<<dim3(D/64, M/128), blk, 0, stream>>>(
      xb, Wvt, bv, bv, Vb16, M, D, D, D);
  // 4-6) ProbSparse attention scoring
  prob_m_kernel<<<dim3(8, L), blk, 0, stream>>>(QKb, idx, Mbuf);
  topk_kernel<<<B*H, dim3(64), 0, stream>>>(Mbuf, Mtop);
  attn_p1_kernel<<<dim3(NJC, H, B), dim3(320), 0, stream>>>(QKb, Vb16, Mtop, pmax, psum, pv);
  // 7) context = cumsum(V)
  cumsum_pass1<<<dim3(D/512, NCHUNK, B), blk, 0, stream>>>(Vb16, csum);
  cumsum_pass2<<<dim3(D/512, NCHUNK, B), blk, 0, stream>>>(Vb16, csum, ctx16);
  // 8) attn combine + scatter
  attn_p2_kernel<<<B*H*U, dim3(64), 0, stream>>>(pmax, psum, pv, Mtop, ctx16);
  // 9) output projection -> bf16 AO
  gemm_kernel<64,3,false,true,false,false><<<dim3(D/64, M/128), blk, 0, stream>>>(
      ctx16, Wot, bo, bo, AO16, M, D, D, D);
  // 10) LN1 -> bf16 residual
  add_ln_kernel<false><<<B*L/4, blk, 0, stream>>>(x, AO16, g1, be1, nullptr, x1b);
  // 11) FF1 via 8-phase 256x256 (bias+ReLU, bf16 out)
  gemm_ff1_8ph_kernel<<<dim3(FFD/256, M/256), dim3(512), 0, stream>>>(
      x1b, W1t, b1, ff1b, M, FFD, D);
  // 12) FF2 -> bf16
  gemm_kernel<64,3,false,true,false,false><<<dim3(D/64, M/128), blk, 0, stream>>>(
      ff1b, W2t, b2, b2, ff2_16, M, D, FFD, FFD);
  // 13) LN2 -> f32 out
  add_ln_kernel<true><<<B*L/4, blk, 0, stream>>>(x1b, ff2_16, g2, be2, out,
                                                 (unsigned short*)nullptr);
}

// Round 16
// 334.388 us; speedup vs baseline: 1.0239x; 1.0239x over previous
//
#include <hip/hip_runtime.h>
#include <hip/hip_bf16.h>
#include <hip/hip_fp16.h>
#include <math.h>

constexpr int B = 2, L = 2048, D = 1024, H = 16, DH = 64, FFD = 4096;
constexpr int S = 40;   // sample_k
constexpr int U = 40;   // n_top
constexpr float EPS = 1e-5f;
constexpr int NCHUNK = 32;
constexpr int CHLEN = L / NCHUNK;   // 64
constexpr int LD3 = 3 * D;          // QK split GEMM K' (3072)
constexpr int LD2 = 2 * D;          // QK output row stride
constexpr int LDA2 = 2 * D;         // A2 row stride [hi|lo]
constexpr int JT = 128;             // attn j-chunk
constexpr int NJC = L / JT;         // 16

typedef __attribute__((ext_vector_type(8))) short short8;      // 8 bf16/f16 bits
typedef __attribute__((ext_vector_type(8))) _Float16 half8;
typedef __attribute__((ext_vector_type(4))) float f32x4;

__device__ __forceinline__ unsigned short f2bf(float v) {
  __hip_bfloat16 h = __float2bfloat16(v);
  return __builtin_bit_cast(unsigned short, h);
}
__device__ __forceinline__ float bf2f(unsigned short u) {
  unsigned int x = ((unsigned int)u) << 16;
  return __builtin_bit_cast(float, x);
}
__device__ __forceinline__ unsigned short f2h(float v) {
  __half h = __float2half(v);
  return __builtin_bit_cast(unsigned short, h);
}
__device__ __forceinline__ float h2f(unsigned short u) {
  return __half2float(__builtin_bit_cast(__half, u));
}

__device__ __forceinline__ void gload16(const void* g, void* l) {
  __builtin_amdgcn_global_load_lds(
      (const __attribute__((address_space(1))) void*)g,
      (__attribute__((address_space(3))) void*)l, 16, 0, 0);
}

// ======== pipelined MFMA GEMM: 128xGBN tile, BK=64, DOUBLE-buffered LDS =====
// (2-barrier structure; QK / V / Wo / FF2. QK NOTE [round-15 lesson]: the
// 8-phase 256x128 port REGRESSED (57 -> 69.6 us, MfmaUtil 40 -> 31%) — its
// 64x64 wave-tile is LDS-read-bound (32 MFMA ~155cyc vs 16 ds_reads ~192cyc)
// and 96KB LDS = 1 block/CU kills cross-block overlap. 8-phase only pays at
// wave-tile 128x64 (FF1). QK stays here: 2 blocks/CU, ~904 TF = its band.)
// DUPA (QK 3-term f16 split, verified): A=[hi|lo] KA=2048; B=[Whi|Wlo|Whi]
// K=3072; tiles >=16 re-read A cols via akt=kt-16. ROUND-12 LESSON: 2-term
// (~2e-3 M-error) FLIPS top-k — selection boundary needs <=1e-5.
template<int GBN, int MINB, bool RELU, bool OUT_BF16, bool F16, bool DUPA>
__global__ __launch_bounds__(256, MINB) void gemm_kernel(
    const unsigned short* __restrict__ A,    // [M][KA] bits
    const unsigned short* __restrict__ Bt,   // [N][K] bits
    const float* __restrict__ bias,          // [N] (or [D] when DUPA)
    const float* __restrict__ biasB,         // [D] second half when DUPA
    void* __restrict__ C, int M, int N, int K, int KA) {
  constexpr int GBM = 128, GBK = 64;
  constexpr int ABUF = GBM * GBK;
  constexpr int BBUF = GBN * GBK;
  constexpr int BUFS = ABUF + BBUF;
  constexpr int NI = GBN / 32;
  constexpr int NLOADS = 4 + GBN / 32;
  __shared__ short lds[2 * BUFS];

  const int tid  = threadIdx.x;
  const int lane = tid & 63;
  const int wid  = tid >> 6;
  const int wr = wid >> 1;
  const int wc = wid & 1;

  const int nwg  = gridDim.x * gridDim.y;
  const int orig = blockIdx.y * gridDim.x + blockIdx.x;
  const int wg   = (orig & 7) * (nwg >> 3) + (orig >> 3);
  const int bm = (wg / gridDim.x) * GBM;
  const int bn = (wg % gridDim.x) * GBN;

  const int srow  = lane >> 3;
  const int sslot = (lane & 7) ^ srow;
  const unsigned short* aS = A  + (size_t)(bm + wid * 8 + srow) * KA + sslot * 8;
  const unsigned short* bS = Bt + (size_t)(bn + wid * 8 + srow) * K  + sslot * 8;
  short* la0 = lds + wid * 8 * GBK;
  short* lb0 = lds + ABUF + wid * 8 * GBK;

  auto STAGE = [&](int buf, int kt) {
    const int akt = (DUPA && kt >= 16) ? kt - 16 : kt;
    const unsigned short* ap = aS + (size_t)akt * GBK;
    const unsigned short* bp = bS + (size_t)kt  * GBK;
    short* la = la0 + buf * BUFS;
    short* lb = lb0 + buf * BUFS;
    gload16(ap,                   la);
    gload16(ap + (size_t)32 * KA, la + 32 * GBK);
    gload16(ap + (size_t)64 * KA, la + 64 * GBK);
    gload16(ap + (size_t)96 * KA, la + 96 * GBK);
    #pragma unroll
    for (int r = 0; r < GBN / 32; ++r)
      gload16(bp + (size_t)(r * 32) * K, lb + r * 32 * GBK);
  };

  const int fr = lane & 15, g = lane >> 4;
  const int nt = K / GBK;

  STAGE(0, 0);

  f32x4 acc[4][NI] = {};
  int cur = 0;
  for (int t = 0; t < nt; ++t) {
    const int kt = (t + 1 < nt) ? t + 1 : t;
    STAGE(cur ^ 1, kt);
    if constexpr (NLOADS == 8)
      asm volatile("s_waitcnt vmcnt(8)" ::: "memory");
    else
      asm volatile("s_waitcnt vmcnt(6)" ::: "memory");
    __builtin_amdgcn_sched_barrier(0);
    __builtin_amdgcn_s_barrier();

    const short* la = lds + cur * BUFS;
    const short* lb = la + ABUF;
    short8 av[2][4], bv[2][NI];
    #pragma unroll
    for (int kk = 0; kk < 2; ++kk) {
      #pragma unroll
      for (int mi = 0; mi < 4; ++mi) {
        const int row = wr * 64 + mi * 16 + fr;
        av[kk][mi] = *(const short8*)&la[row * GBK + ((((kk << 2) | g) ^ (fr & 7)) << 3)];
      }
      #pragma unroll
      for (int ni = 0; ni < NI; ++ni) {
        const int row = wc * (GBN / 2) + ni * 16 + fr;
        bv[kk][ni] = *(const short8*)&lb[row * GBK + ((((kk << 2) | g) ^ (fr & 7)) << 3)];
      }
    }
    __builtin_amdgcn_s_setprio(1);
    #pragma unroll
    for (int kk = 0; kk < 2; ++kk)
      #pragma unroll
      for (int mi = 0; mi < 4; ++mi)
        #pragma unroll
        for (int ni = 0; ni < NI; ++ni) {
          if constexpr (F16)
            acc[mi][ni] = __builtin_amdgcn_mfma_f32_16x16x32_f16(
                __builtin_bit_cast(half8, av[kk][mi]),
                __builtin_bit_cast(half8, bv[kk][ni]), acc[mi][ni], 0, 0, 0);
          else
            acc[mi][ni] = __builtin_amdgcn_mfma_f32_16x16x32_bf16(
                av[kk][mi], bv[kk][ni], acc[mi][ni], 0, 0, 0);
        }
    __builtin_amdgcn_s_setprio(0);
    asm volatile("s_waitcnt lgkmcnt(0)" ::: "memory");
    __builtin_amdgcn_sched_barrier(0);
    __builtin_amdgcn_s_barrier();
    cur ^= 1;
  }

  #pragma unroll
  for (int ni = 0; ni < NI; ++ni) {
    const int col = bn + wc * (GBN / 2) + ni * 16 + fr;
    const float bcol = DUPA ? (col < D ? bias[col] : biasB[col - D]) : bias[col];
    #pragma unroll
    for (int mi = 0; mi < 4; ++mi) {
      #pragma unroll
      for (int j = 0; j < 4; ++j) {
        const int rowg = bm + wr * 64 + mi * 16 + (g << 2) + j;
        float v = acc[mi][ni][j] + bcol;
        if (RELU) v = fmaxf(v, 0.f);
        if (OUT_BF16) ((unsigned short*)C)[(size_t)rowg * N + col] = f2bf(v);
        else          ((float*)C)[(size_t)rowg * N + col] = v;
      }
    }
  }
}

// ======== 8-phase 256x256 MFMA GEMM (FF1: M=4096,N=4096,K=1024) =============
// Works here because wave-tile is 128x64: 64 MFMA (~310cyc) covers 24 ds_reads
// (~288cyc). [round-15: do NOT shrink wave-tile to 64x64 — LDS-read-bound.]
__global__ __launch_bounds__(512, 1) void gemm_ff1_8ph_kernel(
    const unsigned short* __restrict__ A,    // [M][K] bf16 bits
    const unsigned short* __restrict__ Bt,   // [N][K] bf16 bits
    const float* __restrict__ bias,          // [N]
    unsigned short* __restrict__ C, int M, int N, int K) {
  constexpr int BK = 64;
  __shared__ short lds8[2 * 32768];   // 128 KB

  const int tid  = threadIdx.x;
  const int lane = tid & 63;
  const int wid  = tid >> 6;
  const int wrm  = wid >> 2;
  const int wcn  = wid & 3;

  const int nwg  = gridDim.x * gridDim.y;
  const int orig = blockIdx.y * gridDim.x + blockIdx.x;
  const int wg   = (orig & 7) * (nwg >> 3) + (orig >> 3);
  const int bm = (wg / gridDim.x) * 256;
  const int bn = (wg % gridDim.x) * 256;

  const int srow  = lane >> 3;
  const int sslot = (lane & 7) ^ srow;
  const unsigned short* aS = A  + (size_t)(bm + wid * 8 + srow) * K + sslot * 8;
  const unsigned short* bS = Bt + (size_t)(bn + wid * 8 + srow) * K + sslot * 8;
  short* ldsA0 = lds8 + wid * 8 * BK;
  short* ldsB0 = lds8 + 16384 + wid * 8 * BK;

  auto STAGE2 = [&](int buf, int kt, int part) {
    if (part < 2) {
      const unsigned short* ap = aS + (size_t)kt * BK;
      short* la = ldsA0 + buf * 32768;
      const int r0 = part * 128;
      gload16(ap + (size_t)r0 * K,        la + r0 * BK);
      gload16(ap + (size_t)(r0 + 64) * K, la + (r0 + 64) * BK);
    } else {
      const unsigned short* bp = bS + (size_t)kt * BK;
      short* lb = ldsB0 + buf * 32768;
      const int r0 = (part - 2) * 128;
      gload16(bp + (size_t)r0 * K,        lb + r0 * BK);
      gload16(bp + (size_t)(r0 + 64) * K, lb + (r0 + 64) * BK);
    }
  };

  const int fr = lane & 15, g = lane >> 4;
  const int nt = K / BK;

  #pragma unroll
  for (int p = 0; p < 4; ++p) STAGE2(0, 0, p);

  f32x4 acc[8][4] = {};
  short8 av[2][4], bv0[2][2], bv1[2][2];
  int bc = 0;
  for (int t = 0; t < nt; ++t) {
    const int kt = (t + 1 < nt) ? t + 1 : t;
    const short* la = lds8 + bc * 32768;
    const short* lb = la + 16384;

    STAGE2(bc ^ 1, kt, 0);
    asm volatile("s_waitcnt vmcnt(2)" ::: "memory");
    __builtin_amdgcn_sched_barrier(0);
    __builtin_amdgcn_s_barrier();

    #pragma unroll
    for (int kk = 0; kk < 2; ++kk) {
      #pragma unroll
      for (int mi = 0; mi < 4; ++mi) {
        const int row = wrm * 128 + mi * 16 + fr;
        av[kk][mi] = *(const short8*)&la[row * BK + ((((kk << 2) | g) ^ (fr & 7)) << 3)];
      }
      #pragma unroll
      for (int ni = 0; ni < 2; ++ni) {
        const int row = wcn * 64 + ni * 16 + fr;
        bv0[kk][ni] = *(const short8*)&lb[row * BK + ((((kk << 2) | g) ^ (fr & 7)) << 3)];
      }
    }
    asm volatile("s_waitcnt lgkmcnt(0)" ::: "memory");
    __builtin_amdgcn_sched_barrier(0);
    __builtin_amdgcn_s_setprio(1);
    #pragma unroll
    for (int kk = 0; kk < 2; ++kk)
      #pragma unroll
      for (int mi = 0; mi < 4; ++mi)
        #pragma unroll
        for (int ni = 0; ni < 2; ++ni)
          acc[mi][ni] = __builtin_amdgcn_mfma_f32_16x16x32_bf16(
              av[kk][mi], bv0[kk][ni], acc[mi][ni], 0, 0, 0);
    __builtin_amdgcn_s_setprio(0);

    STAGE2(bc ^ 1, kt, 1);
    #pragma unroll
    for (int kk = 0; kk < 2; ++kk)
      #pragma unroll
      for (int ni = 0; ni < 2; ++ni) {
        const int row = wcn * 64 + 32 + ni * 16 + fr;
        bv1[kk][ni] = *(const short8*)&lb[row * BK + ((((kk << 2) | g) ^ (fr & 7)) << 3)];
      }
    asm volatile("s_waitcnt lgkmcnt(0)" ::: "memory");
    __builtin_amdgcn_sched_barrier(0);
    __builtin_amdgcn_s_setprio(1);
    #pragma unroll
    for (int kk = 0; kk < 2; ++kk)
      #pragma unroll
      for (int mi = 0; mi < 4; ++mi)
        #pragma unroll
        for (int ni = 0; ni < 2; ++ni)
          acc[mi][2 + ni] = __builtin_amdgcn_mfma_f32_16x16x32_bf16(
              av[kk][mi], bv1[kk][ni], acc[mi][2 + ni], 0, 0, 0);
    __builtin_amdgcn_s_setprio(0);

    STAGE2(bc ^ 1, kt, 2);
    #pragma unroll
    for (int kk = 0; kk < 2; ++kk)
      #pragma unroll
      for (int mi = 0; mi < 4; ++mi) {
        const int row = wrm * 128 + 64 + mi * 16 + fr;
        av[kk][mi] = *(const short8*)&la[row * BK + ((((kk << 2) | g) ^ (fr & 7)) << 3)];
      }
    asm volatile("s_waitcnt lgkmcnt(0)" ::: "memory");
    __builtin_amdgcn_sched_barrier(0);
    __builtin_amdgcn_s_setprio(1);
    #pragma unroll
    for (int kk = 0; kk < 2; ++kk)
      #pragma unroll
      for (int mi = 0; mi < 4; ++mi)
        #pragma unroll
        for (int ni = 0; ni < 2; ++ni)
          acc[4 + mi][ni] = __builtin_amdgcn_mfma_f32_16x16x32_bf16(
              av[kk][mi], bv0[kk][ni], acc[4 + mi][ni], 0, 0, 0);
    __builtin_amdgcn_s_setprio(0);

    STAGE2(bc ^ 1, kt, 3);
    __builtin_amdgcn_s_setprio(1);
    #pragma unroll
    for (int kk = 0; kk < 2; ++kk)
      #pragma unroll
      for (int mi = 0; mi < 4; ++mi)
        #pragma unroll
        for (int ni = 0; ni < 2; ++ni)
          acc[4 + mi][2 + ni] = __builtin_amdgcn_mfma_f32_16x16x32_bf16(
              av[kk][mi], bv1[kk][ni], acc[4 + mi][2 + ni], 0, 0, 0);
    __builtin_amdgcn_s_setprio(0);
    __builtin_amdgcn_s_barrier();
    bc ^= 1;
  }

  #pragma unroll
  for (int NJ = 0; NJ < 4; ++NJ) {
    const int col = bn + wcn * 64 + NJ * 16 + fr;
    const float bcol = bias[col];
    #pragma unroll
    for (int MI = 0; MI < 8; ++MI) {
      #pragma unroll
      for (int j = 0; j < 4; ++j) {
        const int rowg = bm + wrm * 128 + MI * 16 + (g << 2) + j;
        float v = fmaxf(acc[MI][NJ][j] + bcol, 0.f);
        C[(size_t)rowg * N + col] = f2bf(v);
      }
    }
  }
}

// ===== fused prep (one launch, block ranges): =====
__global__ __launch_bounds__(256) void prep_kernel(
    const float* __restrict__ x, unsigned short* __restrict__ A2,
    unsigned short* __restrict__ xb,
    const float* __restrict__ Wq, const float* __restrict__ Wk,
    unsigned short* __restrict__ B2r,
    const float* __restrict__ Wv, const float* __restrict__ Wo,
    const float* __restrict__ W1, const float* __restrict__ W2,
    unsigned short* __restrict__ Wvt, unsigned short* __restrict__ Wot,
    unsigned short* __restrict__ W1t, unsigned short* __restrict__ W2t) {
  const int bid = blockIdx.x;
  __shared__ float tile[32][33];
  if (bid < 4096) {
    const int i = (bid * 256 + threadIdx.x) * 4;
    const int m = i / D, k = i % D;
    const float4 v = *(const float4*)(x + i);
    ushort4 hi, lo, bb;
    hi.x = f2h(v.x); lo.x = f2h(v.x - h2f(hi.x)); bb.x = f2bf(v.x);
    hi.y = f2h(v.y); lo.y = f2h(v.y - h2f(hi.y)); bb.y = f2bf(v.y);
    hi.z = f2h(v.z); lo.z = f2h(v.z - h2f(hi.z)); bb.z = f2bf(v.z);
    hi.w = f2h(v.w); lo.w = f2h(v.w - h2f(hi.w)); bb.w = f2bf(v.w);
    unsigned short* row = A2 + (size_t)m * LDA2;
    *(ushort4*)(row + k)     = hi;
    *(ushort4*)(row + D + k) = lo;
    *(ushort4*)(xb + i) = bb;
    return;
  }
  const int tx = threadIdx.x & 31, ty = threadIdx.x >> 5;
  if (bid < 6144) {
    const int t = bid - 4096;
    const int z = t >> 10;
    const float* W = z ? Wk : Wq;
    unsigned short* outb = B2r + (size_t)z * D * LD3;
    const int bx = ((t & 1023) & 31) * 32;
    const int by = ((t & 1023) >> 5) * 32;
    #pragma unroll
    for (int i = ty; i < 32; i += 8)
      tile[i][tx] = W[(size_t)(by + i) * D + bx + tx];
    __syncthreads();
    #pragma unroll
    for (int i = ty; i < 32; i += 8) {
      const float v = tile[tx][i];
      const unsigned short hi = f2h(v);
      const unsigned short lo = f2h(v - h2f(hi));
      unsigned short* r = outb + (size_t)(bx + i) * LD3 + (by + tx);
      r[0]     = hi;
      r[D]     = lo;
      r[2 * D] = hi;
    }
    return;
  }
  const int tb = bid - 6144;
  const float* W; unsigned short* Wt; int K, N, t;
  if (tb < 1024)      { W = Wv; Wt = Wvt; K = D;   N = D;   t = tb; }
  else if (tb < 2048) { W = Wo; Wt = Wot; K = D;   N = D;   t = tb - 1024; }
  else if (tb < 6144) { W = W1; Wt = W1t; K = D;   N = FFD; t = tb - 2048; }
  else                { W = W2; Wt = W2t; K = FFD; N = D;   t = tb - 6144; }
  const int nx = N / 32;
  const int bx = (t % nx) * 32;
  const int by = (t / nx) * 32;
  #pragma unroll
  for (int i = ty; i < 32; i += 8)
    tile[i][tx] = W[(size_t)(by + i) * N + bx + tx];
  __syncthreads();
  #pragma unroll
  for (int i = ty; i < 32; i += 8)
    Wt[(size_t)(bx + i) * K + by + tx] = f2bf(tile[tx][i]);
}

// ------------- M[b,h,l] = max_s(Q[l]·K[idx[l,s]]) - sum_s(...)/L ------------
__global__ __launch_bounds__(256) void prob_m_kernel(
    const float* __restrict__ QK, const int* __restrict__ idx,
    float* __restrict__ M_) {
  const int combo = blockIdx.x;
  const int b = combo >> 2, hg = combo & 3;
  const int l = blockIdx.y;
  const int tid = threadIdx.x;
  const int wave = tid >> 6;
  const int lane = tid & 63;
  const int h = hg * 4 + wave;
  __shared__ int sidx[S];
  if (tid < S) sidx[tid] = idx[l * S + tid];
  __syncthreads();
  const int dsub = (lane & 15) * 4;
  const int sgrp = lane >> 4;
  const float4 q = *(const float4*)(QK + ((size_t)b * L + l) * LD2 + h * DH + dsub);
  float mx = -INFINITY, sm = 0.f;
  for (int s = sgrp; s < S; s += 4) {
    const float4 kv = *(const float4*)(QK + ((size_t)b * L + sidx[s]) * LD2 + D + h * DH + dsub);
    float p = q.x*kv.x + q.y*kv.y + q.z*kv.z + q.w*kv.w;
    p += __shfl_xor(p, 1);
    p += __shfl_xor(p, 2);
    p += __shfl_xor(p, 4);
    p += __shfl_xor(p, 8);
    mx = fmaxf(mx, p);
    sm += p;
  }
  mx = fmaxf(mx, __shfl_xor(mx, 16));
  mx = fmaxf(mx, __shfl_xor(mx, 32));
  sm += __shfl_xor(sm, 16);
  sm += __shfl_xor(sm, 32);
  if (lane == 0)
    M_[((size_t)b * H + h) * L + l] = mx - sm / (float)L;
}

// ---- exact top-k (k=40, n=2048): single wave, register-resident, no LDS ----
__global__ __launch_bounds__(64) void topk_kernel(
    const float* __restrict__ M_, int* __restrict__ Mtop) {
  const int bh = blockIdx.x;
  const float* row = M_ + (size_t)bh * L;
  const int lane = threadIdx.x;
  float v[32];
  #pragma unroll
  for (int k = 0; k < 32; ++k) v[k] = row[k * 64 + lane];
  for (int u = 0; u < U; ++u) {
    float best = v[0]; int bk = 0;
    #pragma unroll
    for (int k = 1; k < 32; ++k)
      if (v[k] > best) { best = v[k]; bk = k; }
    int bidx = bk * 64 + lane;
    #pragma unroll
    for (int off = 1; off < 64; off <<= 1) {
      const float ov = __shfl_xor(best, off);
      const int   oi = __shfl_xor(bidx, off);
      if (ov > best || (ov == best && oi < bidx)) { best = ov; bidx = oi; }
    }
    if (lane == 0) Mtop[bh * U + u] = bidx;
    if ((bidx & 63) == lane) {
      const int kk = bidx >> 6;
      #pragma unroll
      for (int k = 0; k < 32; ++k) if (k == kk) v[k] = -INFINITY;
    }
  }
}

// ------- attn phase 1: per (b,h,jc) partial softmax + PV over 128 keys ------
__global__ __launch_bounds__(320) void attn_p1_kernel(
    const float* __restrict__ QK, const unsigned short* __restrict__ V16,
    const int* __restrict__ Mtop,
    float* __restrict__ pmax, float* __restrict__ psum, float* __restrict__ pv) {
  const int jc = blockIdx.x, h = blockIdx.y, b = blockIdx.z;
  const int bh = b * H + h;
  const int tid = threadIdx.x;
  const int j0 = jc * JT;
  __shared__ float Qs[U][68];
  __shared__ float KVs[JT][68];
  __shared__ unsigned short ws[U][JT];

  for (int i = tid; i < U * 16; i += 320) {
    const int u = i >> 4, dq = (i & 15) << 2;
    const int row = Mtop[bh * U + u];
    *(float4*)&Qs[u][dq] =
        *(const float4*)(QK + ((size_t)b * L + row) * LD2 + h * DH + dq);
  }
  for (int i = tid; i < JT * 16; i += 320) {
    const int j = i >> 4, dq = (i & 15) << 2;
    *(float4*)&KVs[j][dq] =
        *(const float4*)(QK + ((size_t)b * L + j0 + j) * LD2 + D + h * DH + dq);
  }
  __syncthreads();

  const int u = tid >> 3, jg = tid & 7;
  const int mt = Mtop[bh * U + u];
  float sc[16];
  #pragma unroll
  for (int jt = 0; jt < 16; ++jt) sc[jt] = 0.f;
  for (int dq = 0; dq < 64; dq += 4) {
    const float4 q = *(const float4*)&Qs[u][dq];
    #pragma unroll
    for (int jt = 0; jt < 16; ++jt) {
      const float4 k = *(const float4*)&KVs[jt * 8 + jg][dq];
      sc[jt] += q.x*k.x + q.y*k.y + q.z*k.z + q.w*k.w;
    }
  }
  float m = -INFINITY;
  #pragma unroll
  for (int jt = 0; jt < 16; ++jt) {
    const int j = j0 + jt * 8 + jg;
    sc[jt] = (j <= mt) ? sc[jt] * 0.125f : -INFINITY;
    m = fmaxf(m, sc[jt]);
  }
  m = fmaxf(m, __shfl_xor(m, 1));
  m = fmaxf(m, __shfl_xor(m, 2));
  m = fmaxf(m, __shfl_xor(m, 4));
  float sum = 0.f;
  #pragma unroll
  for (int jt = 0; jt < 16; ++jt) {
    const float e = (sc[jt] == -INFINITY) ? 0.f : expf(sc[jt] - m);
    sum += e;
    ws[u][jt * 8 + jg] = f2bf(e);
  }
  sum += __shfl_xor(sum, 1);
  sum += __shfl_xor(sum, 2);
  sum += __shfl_xor(sum, 4);
  if (jg == 0) {
    pmax[(size_t)(bh * NJC + jc) * U + u] = m;
    psum[(size_t)(bh * NJC + jc) * U + u] = sum;
  }
  __syncthreads();
  for (int i = tid; i < JT * 8; i += 320) {
    const int j = i >> 3, d8 = (i & 7) << 3;
    short8 vv = *(const short8*)(V16 + ((size_t)b * L + j0 + j) * D + h * DH + d8);
    #pragma unroll
    for (int e = 0; e < 8; ++e)
      KVs[j][d8 + e] = bf2f((unsigned short)vv[e]);
  }
  __syncthreads();
  const int d = tid & 63, ug = tid >> 6;
  float acc[8] = {};
  for (int j = 0; j < JT; j += 2) {
    const float v0 = KVs[j][d], v1 = KVs[j + 1][d];
    #pragma unroll
    for (int k = 0; k < 8; ++k) {
      const int uu = ug + k * 5;
      const unsigned int wp = *(const unsigned int*)&ws[uu][j];
      acc[k] = fmaf(bf2f((unsigned short)(wp & 0xffff)), v0, acc[k]);
      acc[k] = fmaf(bf2f((unsigned short)(wp >> 16)), v1, acc[k]);
    }
  }
  #pragma unroll
  for (int k = 0; k < 8; ++k) {
    const int uu = ug + k * 5;
    pv[((size_t)(bh * NJC + jc) * U + uu) * DH + d] = acc[k];
  }
}

// -- attn phase 2: combine 16 chunks per (b,h,u), scatter into ctx16 (bf16) --
__global__ __launch_bounds__(64) void attn_p2_kernel(
    const float* __restrict__ pmax, const float* __restrict__ psum,
    const float* __restrict__ pv, const int* __restrict__ Mtop,
    unsigned short* __restrict__ ctx16) {
  const int bid = blockIdx.x;
  const int u = bid % U, bh = bid / U;
  const int d = threadIdx.x;
  float gmax = -INFINITY;
  for (int c = 0; c < NJC; ++c)
    gmax = fmaxf(gmax, pmax[(size_t)(bh * NJC + c) * U + u]);
  float den = 0.f, num = 0.f;
  for (int c = 0; c < NJC; ++c) {
    const float m = pmax[(size_t)(bh * NJC + c) * U + u];
    if (m == -INFINITY) continue;
    const float s = expf(m - gmax);
    den += psum[(size_t)(bh * NJC + c) * U + u] * s;
    num += pv[((size_t)(bh * NJC + c) * U + u) * DH + d] * s;
  }
  const int h = bh % H, b = bh / H;
  const int l = Mtop[bh * U + u];
  ctx16[((size_t)b * L + l) * D + h * DH + d] = f2bf(num / den);
}

// --------- cumsum(V16) over l: pass1 = per-chunk column sums only -----------
__global__ __launch_bounds__(256) void cumsum_pass1(
    const unsigned short* __restrict__ V16, float* __restrict__ csums) {
  const int cp = blockIdx.x * 256 + threadIdx.x;
  const int ch = blockIdx.y, b = blockIdx.z;
  size_t base = ((size_t)b * L + (size_t)ch * CHLEN) * D + cp * 2;
  float a0 = 0.f, a1 = 0.f;
  for (int i = 0; i < CHLEN; ++i) {
    const unsigned int u = *(const unsigned int*)(V16 + base + (size_t)i * D);
    a0 += bf2f((unsigned short)(u & 0xffff));
    a1 += bf2f((unsigned short)(u >> 16));
  }
  float* cs = csums + ((size_t)b * NCHUNK + ch) * D + cp * 2;
  cs[0] = a0; cs[1] = a1;
}

__global__ __launch_bounds__(256) void cumsum_pass2(
    const unsigned short* __restrict__ V16, const float* __restrict__ csums,
    unsigned short* __restrict__ ctx16) {
  const int cp = blockIdx.x * 256 + threadIdx.x;
  const int ch = blockIdx.y, b = blockIdx.z;
  float a0 = 0.f, a1 = 0.f;
  for (int j = 0; j < ch; ++j) {
    const float* cs = csums + ((size_t)b * NCHUNK + j) * D + cp * 2;
    a0 += cs[0]; a1 += cs[1];
  }
  size_t base = ((size_t)b * L + (size_t)ch * CHLEN) * D + cp * 2;
  for (int i = 0; i < CHLEN; ++i) {
    const size_t o = base + (size_t)i * D;
    const unsigned int u = *(const unsigned int*)(V16 + o);
    a0 += bf2f((unsigned short)(u & 0xffff));
    a1 += bf2f((unsigned short)(u >> 16));
    *(unsigned int*)(ctx16 + o) =
        (unsigned int)f2bf(a0) | ((unsigned int)f2bf(a1) << 16);
  }
}

// -- out = LayerNorm(a + r)*g + be; wave-per-row (4 rows/block, shfl reduce) -
template<bool ABF16>
__global__ __launch_bounds__(256) void add_ln_kernel(
    const void* __restrict__ a_, const unsigned short* __restrict__ r,
    const float* __restrict__ g, const float* __restrict__ be,
    float* __restrict__ out, unsigned short* __restrict__ out16) {
  const int row  = blockIdx.x * 4 + (threadIdx.x >> 6);
  const int lane = threadIdx.x & 63;
  float v[16];
  float s = 0.f;
  #pragma unroll
  for (int j = 0; j < 4; ++j) {
    const int c = j * 256 + lane * 4;
    float4 av;
    if (ABF16) {
      ushort4 ua = *(const ushort4*)((const unsigned short*)a_ + (size_t)row * D + c);
      av.x = bf2f(ua.x); av.y = bf2f(ua.y); av.z = bf2f(ua.z); av.w = bf2f(ua.w);
    } else {
      av = *(const float4*)((const float*)a_ + (size_t)row * D + c);
    }
    const ushort4 ur = *(const ushort4*)(r + (size_t)row * D + c);
    v[j*4+0] = av.x + bf2f(ur.x);
    v[j*4+1] = av.y + bf2f(ur.y);
    v[j*4+2] = av.z + bf2f(ur.z);
    v[j*4+3] = av.w + bf2f(ur.w);
    s += v[j*4+0] + v[j*4+1] + v[j*4+2] + v[j*4+3];
  }
  #pragma unroll
  for (int off = 1; off < 64; off <<= 1) s += __shfl_xor(s, off);
  const float mu = s / (float)D;
  float s2 = 0.f;
  #pragma unroll
  for (int k = 0; k < 16; ++k) { const float dv = v[k] - mu; s2 += dv * dv; }
  #pragma unroll
  for (int off = 1; off < 64; off <<= 1) s2 += __shfl_xor(s2, off);
  const float rstd = rsqrtf(s2 / (float)D + EPS);
  #pragma unroll
  for (int j = 0; j < 4; ++j) {
    const int c = j * 256 + lane * 4;
    const float4 gv = *(const float4*)(g + c);
    const float4 bv = *(const float4*)(be + c);
    float o0 = (v[j*4+0] - mu) * rstd * gv.x + bv.x;
    float o1 = (v[j*4+1] - mu) * rstd * gv.y + bv.y;
    float o2 = (v[j*4+2] - mu) * rstd * gv.z + bv.z;
    float o3 = (v[j*4+3] - mu) * rstd * gv.w + bv.w;
    if (out) {
      float4 ov; ov.x = o0; ov.y = o1; ov.z = o2; ov.w = o3;
      *(float4*)(out + (size_t)row * D + c) = ov;
    }
    if (out16) {
      ushort4 uo;
      uo.x = f2bf(o0); uo.y = f2bf(o1); uo.z = f2bf(o2); uo.w = f2bf(o3);
      *(ushort4*)(out16 + (size_t)row * D + c) = uo;
    }
  }
}

// ----------------------------------------------------------------------------
extern "C" void kernel_launch(void* const* d_in, const int* in_sizes, int n_in,
                              void* d_out, int out_size, void* d_ws, size_t ws_size,
                              hipStream_t stream) {
  const float* x   = (const float*)d_in[0];
  const float* Wq  = (const float*)d_in[1];
  const float* bq  = (const float*)d_in[2];
  const float* Wk  = (const float*)d_in[3];
  const float* bk  = (const float*)d_in[4];
  const float* Wv  = (const float*)d_in[5];
  const float* bv  = (const float*)d_in[6];
  const float* Wo  = (const float*)d_in[7];
  const float* bo  = (const float*)d_in[8];
  const float* g1  = (const float*)d_in[9];
  const float* be1 = (const float*)d_in[10];
  const float* W1  = (const float*)d_in[11];
  const float* b1  = (const float*)d_in[12];
  const float* W2  = (const float*)d_in[13];
  const float* b2  = (const float*)d_in[14];
  const float* g2  = (const float*)d_in[15];
  const float* be2 = (const float*)d_in[16];
  const int*   idx = (const int*)d_in[17];
  float* out = (float*)d_out;

  char* p = (char*)d_ws;
  unsigned short* A2     = (unsigned short*)p;
  unsigned short* AO16   = (unsigned short*)p;
  unsigned short* ff2_16 = (unsigned short*)(p + 8388608);
  unsigned short* xb    = (unsigned short*)(p + 16777216);
  unsigned short* ctx16 = (unsigned short*)(p + 16777216);
  unsigned short* B2 = (unsigned short*)(p + 25165824);
  char* scr = p + 25165824;
  float* Mbuf   = (float*)(scr);
  float* csum   = (float*)(scr + 262144);
  int*   Mtop   = (int*)  (scr + 524288);
  float* pmax   = (float*)(scr + 532480);
  float* psum   = (float*)(scr + 614400);
  float* pv     = (float*)(scr + 696320);
  float*          QKb = (float*)(p + 37748736);
  unsigned short* x1b = (unsigned short*)(p + 54525952);
  unsigned short* ff1b = (unsigned short*)(p + 62914560);
  unsigned short* Vb16 = (unsigned short*)(p + 96468992);
  unsigned short* Wvt = (unsigned short*)(p + 113246208);
  unsigned short* Wot = (unsigned short*)(p + 115343360);
  unsigned short* W1t = (unsigned short*)(p + 117440512);
  unsigned short* W2t = (unsigned short*)(p + 125829120);

  dim3 blk(256);
  const int M = B * L;   // 4096

  // 1) fused prep
  prep_kernel<<<16384, blk, 0, stream>>>(x, A2, xb, Wq, Wk, B2,
                                         Wv, Wo, W1, W2, Wvt, Wot, W1t, W2t);
  // 2) QK via f16 3-term split (fp32-accurate, selection-safe), A-dedup
  //    [2-barrier 128x128, 2 blocks/CU — round-15: 8-phase port regressed]
  gemm_kernel<128,2,false,false,true,true><<<dim3(LD2/128, M/128), blk, 0, stream>>>(
      A2, B2, bq, bk, QKb, M, LD2, LD3, LDA2);
  // 3) V projection -> bf16
  gemm_kernel<64,3,false,true,false,false><<<dim3(D/64, M/128), blk, 0, stream>>>(
      xb, Wvt, bv, bv, Vb16, M, D, D, D);
  // 4-6) ProbSparse attention scoring
  prob_m_kernel<<<dim3(8, L), blk, 0, stream>>>(QKb, idx, Mbuf);
  topk_kernel<<<B*H, dim3(64), 0, stream>>>(Mbuf, Mtop);
  attn_p1_kernel<<<dim3(NJC, H, B), dim3(320), 0, stream>>>(QKb, Vb16, Mtop, pmax, psum, pv);
  // 7) context = cumsum(V)
  cumsum_pass1<<<dim3(D/512, NCHUNK, B), blk, 0, stream>>>(Vb16, csum);
  cumsum_pass2<<<dim3(D/512, NCHUNK, B), blk, 0, stream>>>(Vb16, csum, ctx16);
  // 8) attn combine + scatter
  attn_p2_kernel<<<B*H*U, dim3(64), 0, stream>>>(pmax, psum, pv, Mtop, ctx16);
  // 9) output projection -> bf16 AO
  gemm_kernel<64,3,false,true,false,false><<<dim3(D/64, M/128), blk, 0, stream>>>(
      ctx16, Wot, bo, bo, AO16, M, D, D, D);
  // 10) LN1 -> bf16 residual
  add_ln_kernel<false><<<B*L/4, blk, 0, stream>>>(x, AO16, g1, be1, nullptr, x1b);
  // 11) FF1 via 8-phase 256x256 (bias+ReLU, bf16 out)
  gemm_ff1_8ph_kernel<<<dim3(FFD/256, M/256), dim3(512), 0, stream>>>(
      x1b, W1t, b1, ff1b, M, FFD, D);
  // 12) FF2 -> bf16
  gemm_kernel<64,3,false,true,false,false><<<dim3(D/64, M/128), blk, 0, stream>>>(
      ff1b, W2t, b2, b2, ff2_16, M, D, FFD, FFD);
  // 13) LN2 -> f32 out
  add_ln_kernel<true><<<B*L/4, blk, 0, stream>>>(x1b, ff2_16, g2, be2, out,
                                                 (unsigned short*)nullptr);
}